// Round 10
// baseline (168.726 us; speedup 1.0000x reference)
//
#include <hip/hip_runtime.h>
#include <math.h>
#include <stdint.h>

// Video Swin shifted-window attention, fully fused, TWO windows per block.
// Round 10: waves 0-7 -> window 2*blockIdx, waves 8-15 -> window 2*blockIdx+1.
// Two independent per-window dependency chains share the CU so stalls in one
// (staging latency, softmax VALU chain, barrier skew) overlap the other's
// MFMA/LDS work. Per-window LDS = 80896 B (x2 = 158KB > 1 block/CU, same
// 16-wave occupancy as before -- the win is ILP, not occupancy):
//   q/O [98][128] swz2 | k [98][128] swz2 | xv = x[112][128] swz2 -> vT[128][120] linear
// vT unswizzled: stride 240B = 15 chunks -> natural bank rotation (like +1 pad).
// v accumulators live in registers across the x->vT overwrite barrier.
// Phase 2 = R8/R9-proven 32x32 P-in-register path (16 tasks/window, 2 passes,
// jt=3 upper half dropped: PV K=112). Proj fused (phase 3).

#define LOG2E   1.4426950408889634f
#define MASKNEG (-144.26950408889634f)   // -100 * LOG2E

typedef __attribute__((ext_vector_type(8)))  short    bf16x8;
typedef __attribute__((ext_vector_type(4)))  float    f32x4;
typedef __attribute__((ext_vector_type(16))) float    f32x16;
typedef __attribute__((ext_vector_type(4)))  unsigned uint32x4;

__device__ __forceinline__ unsigned short cvt1(float f) {
    __bf16 h = (__bf16)f;
    return __builtin_bit_cast(unsigned short, h);
}
__device__ __forceinline__ unsigned cvt2(float lo, float hi) {
    return (unsigned)cvt1(lo) | ((unsigned)cvt1(hi) << 16);
}
__device__ __forceinline__ void pswap(unsigned &a, unsigned &b) {
    asm volatile("v_permlane32_swap_b32 %0, %1" : "+v"(a), "+v"(b));
}
__device__ __forceinline__ int tok_code(int t) {
    int pd = t / 49;
    int r  = t - pd * 49;
    int ph = r / 7;
    int pw = r - ph * 7;
    return (pd >= 1 ? 1 : 0) | (ph >= 4 ? 2 : 0) | (pw >= 4 ? 4 : 0);
}
// XOR-swizzled offset in stride-128 bf16 tiles (16B chunks)
__device__ __forceinline__ int swz2(int row, int col) {
    return row * 128 + ((((col >> 3) ^ (row & 7) ^ ((row >> 3) & 3)) & 15) << 3) + (col & 7);
}

// ---------- prep: weights -> bf16, gathered 32x32 bias table (R9-proven) ----------
__global__ void prep(const float* __restrict__ qkv_w,
                     const float* __restrict__ proj_w,
                     const float* __restrict__ rpb_table,
                     const int*   __restrict__ rel_index,
                     unsigned short* __restrict__ wqkv,
                     unsigned short* __restrict__ wproj,
                     float* __restrict__ bm) {
    int tid = blockIdx.x * blockDim.x + threadIdx.x;
    int stride = gridDim.x * blockDim.x;
    for (int i = tid; i < 384 * 128; i += stride) wqkv[i]  = cvt1(qkv_w[i]);
    for (int i = tid; i < 128 * 128; i += stride) wproj[i] = cvt1(proj_w[i]);
    // bm[cls8][h4][it4][jt4][q4][hi2][il32][e4] f32, *LOG2E, mask folded, j>=98 -inf
    for (int idx = tid; idx < 524288; idx += stride) {
        int e  = idx & 3;
        int il = (idx >> 2) & 31;
        int hi = (idx >> 7) & 1;
        int q  = (idx >> 8) & 3;
        int jt = (idx >> 10) & 3;
        int it = (idx >> 12) & 3;
        int h  = (idx >> 14) & 3;
        int cl = (idx >> 16);
        int i = it * 32 + il;
        int j = jt * 32 + q * 8 + hi * 4 + e;
        float v;
        if (j >= 98) v = -INFINITY;
        else if (i >= 98) v = 0.f;
        else {
            float bias = rpb_table[rel_index[i * 98 + j] * 4 + h];
            bool  msk  = (((unsigned)tok_code(i) ^ (unsigned)tok_code(j)) & (unsigned)cl) != 0;
            v = bias * LOG2E + (msk ? MASKNEG : 0.f);
        }
        bm[idx] = v;
    }
}

// ---------- main: two windows per block ----------
__global__ __launch_bounds__(1024, 4)
void swin_fused2(const float* __restrict__ x,
                 const float* __restrict__ qkv_b,
                 const float* __restrict__ proj_b,
                 const unsigned short* __restrict__ wqkv,
                 const unsigned short* __restrict__ wproj,
                 const float* __restrict__ bm,
                 float* __restrict__ out)
{
    extern __shared__ unsigned short lds[];
    const int tid  = threadIdx.x;
    const int wg   = tid >> 9;          // window half 0/1
    const int wtid = tid & 511;
    const int lw   = wtid >> 6;         // local wave 0..7
    const int lane = tid & 63;
    const int l4   = lane >> 4;
    const int lc   = lane & 15;
    const int b    = blockIdx.x * 2 + wg;

    unsigned short* q_w  = lds + wg * 40448;  // [98][128] swz2; O overwrites
    unsigned short* k_w  = q_w + 12544;       // [98][128] swz2
    unsigned short* xv_w = q_w + 25088;       // x[112][128] swz2, then vT[128][120] linear

    // ---- stage x (this window's 512 threads), pad rows 98..111 zeroed ----
    {
        const float* xb = x + (size_t)b * 12544;
#pragma unroll
        for (int i = 0; i < 7; ++i) {
            int idx = wtid + i * 512;
            int tok = idx >> 5;
            int c   = (idx & 31) << 2;
            float4 v;
            if (tok < 98) v = *(const float4*)(xb + tok * 128 + c);
            else { v.x = 0.f; v.y = 0.f; v.z = 0.f; v.w = 0.f; }
            uint2 hv; hv.x = cvt2(v.x, v.y); hv.y = cvt2(v.z, v.w);
            *(uint2*)(xv_w + swz2(tok, c)) = hv;
        }
    }
    __syncthreads();

    // ---- Phase 1: wave lw computes q-tile lw, k-tile lw, v-tile lw (to regs) ----
    f32x4 vacc[7];
    {
        bf16x8 wfq[4], wfk[4], wfv[4];
        const unsigned short* rq = wqkv + (lw * 16 + lc) * 128;
        const unsigned short* rk = wqkv + (128 + lw * 16 + lc) * 128;
        const unsigned short* rv = wqkv + (256 + lw * 16 + lc) * 128;
#pragma unroll
        for (int kt = 0; kt < 4; ++kt) {
            wfq[kt] = *(const bf16x8*)(rq + kt * 32 + l4 * 8);
            wfk[kt] = *(const bf16x8*)(rk + kt * 32 + l4 * 8);
            wfv[kt] = *(const bf16x8*)(rv + kt * 32 + l4 * 8);
        }
        f32x4 bq, bk, bv;
#pragma unroll
        for (int r = 0; r < 4; ++r) {
            bq[r] = qkv_b[lw * 16 + l4 * 4 + r];
            bk[r] = qkv_b[128 + lw * 16 + l4 * 4 + r];
            bv[r] = qkv_b[256 + lw * 16 + l4 * 4 + r];
        }
        const float qs = 0.17677669529663689f * LOG2E;
#pragma unroll
        for (int t = 0; t < 7; ++t) {
            bf16x8 xf[4];
#pragma unroll
            for (int kt = 0; kt < 4; ++kt)
                xf[kt] = *(bf16x8*)(xv_w + swz2(t * 16 + lc, kt * 32 + l4 * 8));
            f32x4 aq = bq, ak = bk, av = bv;
#pragma unroll
            for (int kt = 0; kt < 4; ++kt) {
                aq = __builtin_amdgcn_mfma_f32_16x16x32_bf16(wfq[kt], xf[kt], aq, 0, 0, 0);
                ak = __builtin_amdgcn_mfma_f32_16x16x32_bf16(wfk[kt], xf[kt], ak, 0, 0, 0);
                av = __builtin_amdgcn_mfma_f32_16x16x32_bf16(wfv[kt], xf[kt], av, 0, 0, 0);
            }
            vacc[t] = av;
            int tok = t * 16 + lc;
            if (tok < 98) {
                uint2 hq; hq.x = cvt2(aq[0] * qs, aq[1] * qs); hq.y = cvt2(aq[2] * qs, aq[3] * qs);
                *(uint2*)(q_w + swz2(tok, lw * 16 + l4 * 4)) = hq;
                uint2 hk; hk.x = cvt2(ak[0], ak[1]); hk.y = cvt2(ak[2], ak[3]);
                *(uint2*)(k_w + swz2(tok, lw * 16 + l4 * 4)) = hk;
            }
        }
    }
    __syncthreads();   // all x reads done; xv region may now become vT

    // ---- vT[128][120] (linear, natural bank rotation) over the x region ----
    {
        const int rb = lw * 16 + l4 * 4;
#pragma unroll
        for (int t = 0; t < 7; ++t) {
            int tok = t * 16 + lc;
            xv_w[(rb + 0) * 120 + tok] = cvt1(vacc[t][0]);
            xv_w[(rb + 1) * 120 + tok] = cvt1(vacc[t][1]);
            xv_w[(rb + 2) * 120 + tok] = cvt1(vacc[t][2]);
            xv_w[(rb + 3) * 120 + tok] = cvt1(vacc[t][3]);
        }
    }
    __syncthreads();

    // ---- Phase 2: 32x32 attention, 16 tasks/window over 8 waves (2 passes) ----
    {
        const int wi = b & 255;
        const unsigned cls =
            ((wi >> 6) == 3 ? 1u : 0u) | (((wi >> 3) & 7) == 7 ? 2u : 0u) | ((wi & 7) == 7 ? 4u : 0u);
        const int il  = lane & 31;
        const int hi2 = lane >> 5;

#pragma unroll
        for (int p2 = 0; p2 < 2; ++p2) {
            const int task  = lw + (p2 << 3);
            const int h     = task >> 2;       // pass0: h=0,1; pass1: h=2,3 (disjoint q cols)
            const int itile = task & 3;
            const int i_tok = itile * 32 + il;

            f32x16 S[4];
            const float* tb = bm + (((size_t)(cls * 4 + h) * 4 + itile) * 4) * 1024 + hi2 * 128 + il * 4;
#pragma unroll
            for (int jt = 0; jt < 4; ++jt)
#pragma unroll
                for (int q = 0; q < 4; ++q) {
                    f32x4 v = *(const f32x4*)(tb + (jt * 8 + q * 2) * 128);
                    S[jt][q * 4 + 0] = v[0]; S[jt][q * 4 + 1] = v[1];
                    S[jt][q * 4 + 2] = v[2]; S[jt][q * 4 + 3] = v[3];
                }

            bf16x8 qfa = *(bf16x8*)(q_w + swz2(i_tok, h * 32 + hi2 * 8));
            bf16x8 qfb = *(bf16x8*)(q_w + swz2(i_tok, h * 32 + 16 + hi2 * 8));
#pragma unroll
            for (int jt = 0; jt < 4; ++jt) {
                bf16x8 ka = *(bf16x8*)(k_w + swz2(jt * 32 + il, h * 32 + hi2 * 8));
                bf16x8 kb = *(bf16x8*)(k_w + swz2(jt * 32 + il, h * 32 + 16 + hi2 * 8));
                S[jt] = __builtin_amdgcn_mfma_f32_32x32x16_bf16(ka, qfa, S[jt], 0, 0, 0);
                S[jt] = __builtin_amdgcn_mfma_f32_32x32x16_bf16(kb, qfb, S[jt], 0, 0, 0);
            }

            // softmax over j (j>=98 are -inf): skip S[3][8..15] (j=112..127)
            float m = S[0][0];
#pragma unroll
            for (int jt = 0; jt < 4; ++jt)
#pragma unroll
                for (int r = 0; r < 16; ++r) {
                    if (jt == 3 && r >= 8) continue;
                    if (!(jt == 0 && r == 0)) m = fmaxf(m, S[jt][r]);
                }
            m = fmaxf(m, __shfl_xor(m, 32));

            float l = 0.f;
            unsigned dw[4][8];
#pragma unroll
            for (int jt = 0; jt < 4; ++jt) {
                const int dmax = (jt == 3) ? 4 : 8;
#pragma unroll
                for (int d = 0; d < 8; ++d) {
                    if (d >= dmax) continue;
                    float p0 = exp2f(S[jt][2 * d]     - m);
                    float p1 = exp2f(S[jt][2 * d + 1] - m);
                    l += p0 + p1;
                    dw[jt][d] = cvt2(p0, p1);
                }
            }
            l += __shfl_xor(l, 32);

#pragma unroll
            for (int jt = 0; jt < 4; ++jt) {
                pswap(dw[jt][0], dw[jt][2]);
                pswap(dw[jt][1], dw[jt][3]);
                if (jt < 3) {
                    pswap(dw[jt][4], dw[jt][6]);
                    pswap(dw[jt][5], dw[jt][7]);
                }
            }

            // PV: K = 112 (7 MFMAs); vT linear [128][120]
            f32x16 O = {0.f,0.f,0.f,0.f,0.f,0.f,0.f,0.f,0.f,0.f,0.f,0.f,0.f,0.f,0.f,0.f};
#pragma unroll
            for (int jt = 0; jt < 4; ++jt)
#pragma unroll
                for (int p = 0; p < 2; ++p) {
                    if (jt == 3 && p == 1) continue;
                    bf16x8 vf = *(bf16x8*)(xv_w + (h * 32 + il) * 120 + jt * 32 + p * 16 + hi2 * 8);
                    uint32x4 pu = { dw[jt][p * 4 + 0], dw[jt][p * 4 + 1],
                                    dw[jt][p * 4 + 2], dw[jt][p * 4 + 3] };
                    O = __builtin_amdgcn_mfma_f32_32x32x16_bf16(
                            vf, __builtin_bit_cast(bf16x8, pu), O, 0, 0, 0);
                }

            const float inv = 1.0f / l;
            if (i_tok < 98) {
#pragma unroll
                for (int rr = 0; rr < 8; ++rr) {
                    int r = rr * 2;
                    int d = (r & 3) + 8 * (r >> 2) + 4 * hi2;
                    *(unsigned*)(q_w + swz2(i_tok, h * 32 + d)) = cvt2(O[r] * inv, O[r + 1] * inv);
                }
            }
        }
    }
    __syncthreads();

    // ---- Phase 3: y^T = Wproj @ O^T (O lives in q region). wave lw -> ct = lw ----
    {
        const int ct = lw;
        bf16x8 pw[4];
#pragma unroll
        for (int kt = 0; kt < 4; ++kt)
            pw[kt] = *(const bf16x8*)(wproj + (ct * 16 + lc) * 128 + kt * 32 + l4 * 8);
        f32x4 pbias;
#pragma unroll
        for (int r = 0; r < 4; ++r) pbias[r] = proj_b[ct * 16 + l4 * 4 + r];

        float* ob = out + (size_t)b * 12544;
#pragma unroll
        for (int t = 0; t < 7; ++t) {
            f32x4 acc = pbias;
#pragma unroll
            for (int kt = 0; kt < 4; ++kt) {
                bf16x8 of = *(bf16x8*)(q_w + swz2(t * 16 + lc, kt * 32 + l4 * 8));
                acc = __builtin_amdgcn_mfma_f32_16x16x32_bf16(pw[kt], of, acc, 0, 0, 0);
            }
            int tok = t * 16 + lc;
            if (tok < 98) {
                float4 st; st.x = acc[0]; st.y = acc[1]; st.z = acc[2]; st.w = acc[3];
                *(float4*)(ob + tok * 128 + ct * 16 + l4 * 4) = st;
            }
        }
    }
}

extern "C" void kernel_launch(void* const* d_in, const int* in_sizes, int n_in,
                              void* d_out, int out_size, void* d_ws, size_t ws_size,
                              hipStream_t stream) {
    const float* x       = (const float*)d_in[0];
    const float* qkv_w   = (const float*)d_in[1];
    const float* qkv_b   = (const float*)d_in[2];
    const float* rpb_tab = (const float*)d_in[3];
    const float* proj_w  = (const float*)d_in[4];
    const float* proj_b  = (const float*)d_in[5];
    const int*   rel_idx = (const int*)d_in[6];
    // d_in[7] (mask) unused: reproduced analytically into bm.
    // ws_size >= 53.6MB proven on this harness (R9 pipe path passed); we use 2.23MB.

    unsigned short* wqkv  = (unsigned short*)d_ws;                   // 98304 B
    unsigned short* wproj = (unsigned short*)((char*)d_ws + 98304);  // 32768 B
    float*          bm    = (float*)((char*)d_ws + 131072);          // 2MB gathered table
    float*          out   = (float*)d_out;

    hipLaunchKernelGGL(prep, dim3(512), dim3(256), 0, stream,
                       qkv_w, proj_w, rpb_tab, rel_idx, wqkv, wproj, bm);

    const int LDS_BYTES = 161792;   // 2 windows x 80896 B
    (void)hipFuncSetAttribute((const void*)swin_fused2,
                              hipFuncAttributeMaxDynamicSharedMemorySize, LDS_BYTES);
    hipLaunchKernelGGL(swin_fused2, dim3(1024), dim3(1024), LDS_BYTES, stream,
                       x, qkv_b, proj_b, wqkv, wproj, bm, out);
}

// Round 11
// 141.243 us; speedup vs baseline: 1.1946x; 1.1946x over previous
//
#include <hip/hip_runtime.h>
#include <math.h>
#include <stdint.h>

// Video Swin shifted-window attention, fully fused, one block per window.
// Round 11: R6 base + two surgical phase-2 chain cuts:
//  (a) no-max softmax: s is bounded (|s*log2e| <= ~34 worst case), masked/pad
//      entries are exactly -inf -> exp2 -> 0. Removes the 112-way max pass and
//      its chain-blocking dependency (exps start as soon as each QK MFMA lands).
//  (b) P redistribution via __shfl (ds_bpermute) instead of the LDS
//      write->read roundtrip: frag[f] = sel(l4>>1, shfl(dw[2jt4+1][f&1], src),
//      shfl(dw[2jt4][f&1], src)), src = ((l4&1)*2+(f>>1))*16+lc.
//      p_lds deleted -> LDS 118784 B, its bank conflicts gone.

#define LOG2E   1.4426950408889634f
#define MASKNEG (-144.26950408889634f)   // -100 * LOG2E

typedef __attribute__((ext_vector_type(8)))  short    bf16x8;
typedef __attribute__((ext_vector_type(4)))  float    f32x4;
typedef __attribute__((ext_vector_type(4)))  unsigned uint32x4;

__device__ __forceinline__ unsigned short cvt1(float f) {
    __bf16 h = (__bf16)f;
    return __builtin_bit_cast(unsigned short, h);
}
__device__ __forceinline__ unsigned cvt2(float lo, float hi) {
    return (unsigned)cvt1(lo) | ((unsigned)cvt1(hi) << 16);
}

// token region code for the shifted-window mask (WIN=(2,7,7), SHIFT=(1,3,3))
__device__ __forceinline__ int tok_code(int t) {
    int pd = t / 49;
    int r  = t - pd * 49;
    int ph = r / 7;
    int pw = r - ph * 7;
    return (pd >= 1 ? 1 : 0) | (ph >= 4 ? 2 : 0) | (pw >= 4 ? 4 : 0);
}

__device__ __forceinline__ float mterm(unsigned pk, int sh, unsigned ci, unsigned cls) {
    return ((((pk >> sh) & 255u) ^ ci) & cls) ? MASKNEG : 0.f;
}

// XOR-swizzled element offset, [rows][128]-bf16 tiles (16B chunks): q/k/xo
__device__ __forceinline__ int swz(int row, int col) {
    return row * 128 + (((col >> 3) ^ (row & 7)) << 3) + (col & 7);
}
// vT swizzle: entropy from row bits [2:0] (reads) and [3:2] (writes)
__device__ __forceinline__ int vswz(int row, int col) {
    return row * 128 + ((((col >> 3) ^ (row & 7) ^ ((row >> 2) & 3)) & 15) << 3) + (col & 7);
}

// ---------------- prep: weights -> bf16, bias tables ----------------
template<bool BIG>
__global__ void prep_kernel(const float* __restrict__ qkv_w,
                            const float* __restrict__ proj_w,
                            const float* __restrict__ rpb_table,
                            const int*   __restrict__ rel_index,
                            unsigned short* __restrict__ wqkv,
                            unsigned short* __restrict__ wproj,
                            void* __restrict__ btab) {
    int tid = blockIdx.x * blockDim.x + threadIdx.x;
    int stride = gridDim.x * blockDim.x;
    for (int i = tid; i < 384 * 128; i += stride) wqkv[i]  = cvt1(qkv_w[i]);
    for (int i = tid; i < 128 * 128; i += stride) wproj[i] = cvt1(proj_w[i]);
    if constexpr (BIG) {
        // bm[cls 8][h 4][i 112][j 112] f32: (bias + mask)*LOG2E; j>=98 -> -inf
        float* bm = (float*)btab;
        for (int idx = tid; idx < 32 * 112 * 112; idx += stride) {
            int ch = idx / 12544; int r = idx - ch * 12544;
            int i  = r / 112;     int j = r - i * 112;
            int cls = ch >> 2, h = ch & 3;
            float v;
            if (i < 98) {
                if (j < 98) {
                    float bias = rpb_table[rel_index[i * 98 + j] * 4 + h];
                    bool  msk  = (((unsigned)tok_code(i) ^ (unsigned)tok_code(j)) & (unsigned)cls) != 0;
                    v = bias * LOG2E + (msk ? MASKNEG : 0.f);
                } else v = -INFINITY;
            } else v = 0.f;
            bm[idx] = v;
        }
    } else {
        unsigned short* biasL = (unsigned short*)btab;
        for (int idx = tid; idx < 4 * 112 * 112; idx += stride) {
            int h = idx / 12544; int r = idx - h * 12544;
            int i = r / 112;     int j = r - i * 112;
            float v;
            if (i < 98) v = (j < 98) ? rpb_table[rel_index[i * 98 + j] * 4 + h] * LOG2E
                                     : -INFINITY;
            else v = 0.f;
            biasL[idx] = cvt1(v);
        }
    }
}

// ---------------- main fused kernel ----------------
template<bool BIG>
__global__ __launch_bounds__(1024)
void swin_main(const float* __restrict__ x,
               const float* __restrict__ qkv_b,
               const float* __restrict__ proj_b,
               const unsigned short* __restrict__ wqkv,
               const unsigned short* __restrict__ wproj,
               const void* __restrict__ btab,
               float* __restrict__ out)
{
    extern __shared__ unsigned short lds[];
    unsigned short* q_lds  = lds;            // [112][128] bf16, swz
    unsigned short* k_lds  = lds + 14336;    // [112][128] swz
    unsigned short* vT_lds = lds + 28672;    // [128][128] vswz (cols 112..127 zero)
    unsigned short* xo_lds = lds + 45056;    // [112][128] swz; x then O
    // total 59392 ush = 118784 B (p_lds removed)

    const int b    = blockIdx.x;
    const int tid  = threadIdx.x;
    const int wv   = tid >> 6;    // 0..15
    const int lane = tid & 63;
    const int l4   = lane >> 4;   // 0..3
    const int lc   = lane & 15;   // 0..15

    // zero vT pad cols 112..127 (128 rows x 16 cols = 2048 ushorts, 2/thread)
    {
        int idx2 = tid * 2;
        int row  = idx2 >> 4;
        int c    = 112 + (idx2 & 15);
        *(unsigned int*)(vT_lds + vswz(row, c)) = 0u;
    }

    // stage x -> xo_lds as bf16 (pad rows 98..111 zeroed)
    {
        const float* xb = x + (size_t)b * 12544;
        for (int idx = tid; idx < 3584; idx += 1024) {
            int tok = idx >> 5;
            int c   = (idx & 31) << 2;
            float4 v;
            if (tok < 98) v = *(const float4*)(xb + tok * 128 + c);
            else { v.x = 0.f; v.y = 0.f; v.z = 0.f; v.w = 0.f; }
            uint2 hv; hv.x = cvt2(v.x, v.y); hv.y = cvt2(v.z, v.w);
            *(uint2*)(xo_lds + swz(tok, c)) = hv;
        }
    }
    __syncthreads();

    // ---- Phase 1: QKV' = Wqkv @ X^T ----
    {
        const int ct = wv;
        bf16x8 wf[4];
        f32x4  bias;
        const unsigned short* wrow = wqkv + (ct * 16 + lc) * 128;
#pragma unroll
        for (int kt = 0; kt < 4; ++kt) wf[kt] = *(const bf16x8*)(wrow + kt * 32 + l4 * 8);
#pragma unroll
        for (int r = 0; r < 4; ++r) bias[r] = qkv_b[ct * 16 + l4 * 4 + r];
        const bool  isq = (ct < 8);
        const float qs  = 0.17677669529663689f * LOG2E;  // scale*log2e folded into q
#pragma unroll
        for (int t = 0; t < 7; ++t) {
            bf16x8 xf[4];
#pragma unroll
            for (int kt = 0; kt < 4; ++kt)
                xf[kt] = *(bf16x8*)(xo_lds + swz(t * 16 + lc, kt * 32 + l4 * 8));
            f32x4 acc = bias;
#pragma unroll
            for (int kt = 0; kt < 4; ++kt)
                acc = __builtin_amdgcn_mfma_f32_16x16x32_bf16(wf[kt], xf[kt], acc, 0, 0, 0);
            int tok = t * 16 + lc;
            if (isq) {
                uint2 hv; hv.x = cvt2(acc[0] * qs, acc[1] * qs); hv.y = cvt2(acc[2] * qs, acc[3] * qs);
                *(uint2*)(q_lds + swz(tok, ct * 16 + l4 * 4)) = hv;
            } else {
                uint2 hv; hv.x = cvt2(acc[0], acc[1]); hv.y = cvt2(acc[2], acc[3]);
                *(uint2*)(k_lds + swz(tok, (ct - 8) * 16 + l4 * 4)) = hv;
            }
        }
        // v: wave pair (wv>>1) owns channel block vd, halves split by wv&1
        const int vd = (wv >> 1) * 16;
        bf16x8 wf2[4];
        const unsigned short* wrow2 = wqkv + (256 + vd + lc) * 128;
#pragma unroll
        for (int kt = 0; kt < 4; ++kt) wf2[kt] = *(const bf16x8*)(wrow2 + kt * 32 + l4 * 8);
        f32x4 bias2;
#pragma unroll
        for (int r = 0; r < 4; ++r) bias2[r] = qkv_b[256 + vd + l4 * 4 + r];
        const int t0 = (wv & 1) ? 4 : 0, t1 = (wv & 1) ? 7 : 4;
        for (int t = t0; t < t1; ++t) {
            bf16x8 xf[4];
#pragma unroll
            for (int kt = 0; kt < 4; ++kt)
                xf[kt] = *(bf16x8*)(xo_lds + swz(t * 16 + lc, kt * 32 + l4 * 8));
            f32x4 acc = bias2;
#pragma unroll
            for (int kt = 0; kt < 4; ++kt)
                acc = __builtin_amdgcn_mfma_f32_16x16x32_bf16(wf2[kt], xf[kt], acc, 0, 0, 0);
            int tok = t * 16 + lc;
            const int rb = vd + l4 * 4;
            vT_lds[vswz(rb + 0, tok)] = cvt1(acc[0]);
            vT_lds[vswz(rb + 1, tok)] = cvt1(acc[1]);
            vT_lds[vswz(rb + 2, tok)] = cvt1(acc[2]);
            vT_lds[vswz(rb + 3, tok)] = cvt1(acc[3]);
        }
    }
    __syncthreads();

    // ---- Phase 2: attention. 28 tasks (head,i-tile) over 16 waves, 2 passes ----
    const int wi  = b & 255;
    const unsigned int cls =
        ((wi >> 6) == 3 ? 1u : 0u) | (((wi >> 3) & 7) == 7 ? 2u : 0u) | ((wi & 7) == 7 ? 4u : 0u);

    unsigned int jcp[7];   // packed region codes (small path only)
    if constexpr (!BIG) {
#pragma unroll
        for (int jt = 0; jt < 7; ++jt) {
            int jb = jt * 16 + l4 * 4;
            unsigned int p = 0;
#pragma unroll
            for (int r = 0; r < 4; ++r) p |= (unsigned)tok_code(jb + r < 98 ? jb + r : 0) << (8 * r);
            jcp[jt] = p;
        }
    }

    const int  srcA = ((l4 & 1) * 2) * 16 + lc;   // P-redistribution source lanes
    const int  srcB = srcA + 16;
    const bool phi  = (l4 >> 1) != 0;

    for (int pass = 0; pass < 2; ++pass) {
        int task = wv + (pass << 4);
        if (task >= 28) break;
        int h  = task / 7;
        int it = task - h * 7;
        const int i_tok = it * 16 + lc;
        const bf16x8 qfrag = *(bf16x8*)(q_lds + swz(i_tok, h * 32 + l4 * 8));

        // prefetch all 7 C-operands (bias+mask) into regs so loads overlap
        f32x4 cvec[7];
        if constexpr (BIG) {
            const float* bmrow = (const float*)btab + ((size_t)((int)cls * 4 + h) * 112 + i_tok) * 112;
#pragma unroll
            for (int jt = 0; jt < 7; ++jt)
                cvec[jt] = *(const f32x4*)(bmrow + jt * 16 + l4 * 4);
        } else {
            const unsigned short* brow = (const unsigned short*)btab + (h * 112 + i_tok) * 112;
            const unsigned int ci = (unsigned)tok_code(i_tok < 98 ? i_tok : 0);
            ushort4 bb[7];
#pragma unroll
            for (int jt = 0; jt < 7; ++jt)
                bb[jt] = *(const ushort4*)(brow + jt * 16 + l4 * 4);
#pragma unroll
            for (int jt = 0; jt < 7; ++jt) {
                cvec[jt][0] = __builtin_bit_cast(float, (unsigned)bb[jt].x << 16) + mterm(jcp[jt], 0,  ci, cls);
                cvec[jt][1] = __builtin_bit_cast(float, (unsigned)bb[jt].y << 16) + mterm(jcp[jt], 8,  ci, cls);
                cvec[jt][2] = __builtin_bit_cast(float, (unsigned)bb[jt].z << 16) + mterm(jcp[jt], 16, ci, cls);
                cvec[jt][3] = __builtin_bit_cast(float, (unsigned)bb[jt].w << 16) + mterm(jcp[jt], 24, ci, cls);
            }
        }

        f32x4 s[7];
#pragma unroll
        for (int jt = 0; jt < 7; ++jt) {
            bf16x8 kfrag = *(bf16x8*)(k_lds + swz(jt * 16 + lc, h * 32 + l4 * 8));
            s[jt] = __builtin_amdgcn_mfma_f32_16x16x32_bf16(kfrag, qfrag, cvec[jt], 0, 0, 0);
        }

        // no-max softmax: exp2 directly (masked/pad -> -inf -> 0); pack to bf16
        float lsum = 0.f;
        unsigned dw[8][2];
#pragma unroll
        for (int jt = 0; jt < 7; ++jt) {
            float p0 = exp2f(s[jt][0]);
            float p1 = exp2f(s[jt][1]);
            float p2 = exp2f(s[jt][2]);
            float p3 = exp2f(s[jt][3]);
            lsum += (p0 + p1) + (p2 + p3);
            dw[jt][0] = cvt2(p0, p1);
            dw[jt][1] = cvt2(p2, p3);
        }
        dw[7][0] = 0u; dw[7][1] = 0u;   // j = 112..127 pad

        // PV with in-register P redistribution (no LDS roundtrip)
        f32x4 o0 = {0.f, 0.f, 0.f, 0.f}, o1 = {0.f, 0.f, 0.f, 0.f};
#pragma unroll
        for (int jt4 = 0; jt4 < 4; ++jt4) {
            unsigned a0 = dw[2 * jt4][0],     a1 = dw[2 * jt4][1];
            unsigned b0 = dw[2 * jt4 + 1][0], b1 = dw[2 * jt4 + 1][1];
            unsigned xA0 = __shfl((int)a0, srcA), yA0 = __shfl((int)b0, srcA);
            unsigned xA1 = __shfl((int)a1, srcA), yA1 = __shfl((int)b1, srcA);
            unsigned xB0 = __shfl((int)a0, srcB), yB0 = __shfl((int)b0, srcB);
            unsigned xB1 = __shfl((int)a1, srcB), yB1 = __shfl((int)b1, srcB);
            uint32x4 pu = { phi ? yA0 : xA0, phi ? yA1 : xA1,
                            phi ? yB0 : xB0, phi ? yB1 : xB1 };
            bf16x8 pfrag = __builtin_bit_cast(bf16x8, pu);
            bf16x8 va = *(bf16x8*)(vT_lds + vswz(h * 32 + lc,      jt4 * 32 + l4 * 8));
            bf16x8 vb = *(bf16x8*)(vT_lds + vswz(h * 32 + 16 + lc, jt4 * 32 + l4 * 8));
            o0 = __builtin_amdgcn_mfma_f32_16x16x32_bf16(va, pfrag, o0, 0, 0, 0);
            o1 = __builtin_amdgcn_mfma_f32_16x16x32_bf16(vb, pfrag, o1, 0, 0, 0);
        }
        lsum += __shfl_xor(lsum, 16);
        lsum += __shfl_xor(lsum, 32);

        float inv = 1.0f / lsum;
        uint2 h0, h1;
        h0.x = cvt2(o0[0] * inv, o0[1] * inv); h0.y = cvt2(o0[2] * inv, o0[3] * inv);
        h1.x = cvt2(o1[0] * inv, o1[1] * inv); h1.y = cvt2(o1[2] * inv, o1[3] * inv);
        *(uint2*)(xo_lds + swz(i_tok, h * 32 + l4 * 4)) = h0;
        *(uint2*)(xo_lds + swz(i_tok, h * 32 + 16 + l4 * 4)) = h1;
    }
    __syncthreads();

    // ---- Phase 3: y^T = Wproj @ O^T. wave -> ct = wv>>1, token half by wv&1 ----
    {
        const int ct = wv >> 1;
        bf16x8 pw[4];
#pragma unroll
        for (int kt = 0; kt < 4; ++kt)
            pw[kt] = *(const bf16x8*)(wproj + (ct * 16 + lc) * 128 + kt * 32 + l4 * 8);
        f32x4 pbias;
#pragma unroll
        for (int r = 0; r < 4; ++r) pbias[r] = proj_b[ct * 16 + l4 * 4 + r];

        float* ob = out + (size_t)b * 12544;
        const int t0 = (wv & 1) ? 4 : 0, t1 = (wv & 1) ? 7 : 4;
        for (int t = t0; t < t1; ++t) {
            f32x4 acc = pbias;
#pragma unroll
            for (int kt = 0; kt < 4; ++kt) {
                bf16x8 of = *(bf16x8*)(xo_lds + swz(t * 16 + lc, kt * 32 + l4 * 8));
                acc = __builtin_amdgcn_mfma_f32_16x16x32_bf16(pw[kt], of, acc, 0, 0, 0);
            }
            int tok = t * 16 + lc;
            if (tok < 98) {
                float4 st; st.x = acc[0]; st.y = acc[1]; st.z = acc[2]; st.w = acc[3];
                *(float4*)(ob + tok * 128 + ct * 16 + l4 * 4) = st;
            }
        }
    }
}

extern "C" void kernel_launch(void* const* d_in, const int* in_sizes, int n_in,
                              void* d_out, int out_size, void* d_ws, size_t ws_size,
                              hipStream_t stream) {
    const float* x       = (const float*)d_in[0];
    const float* qkv_w   = (const float*)d_in[1];
    const float* qkv_b   = (const float*)d_in[2];
    const float* rpb_tab = (const float*)d_in[3];
    const float* proj_w  = (const float*)d_in[4];
    const float* proj_b  = (const float*)d_in[5];
    const int*   rel_idx = (const int*)d_in[6];
    // d_in[7] (mask) unused: reproduced analytically into the tables.

    unsigned short* wqkv  = (unsigned short*)d_ws;                   // 98304 B
    unsigned short* wproj = (unsigned short*)((char*)d_ws + 98304);  // 32768 B
    void*           btab  = (void*)((char*)d_ws + 131072);           // bias table
    float*          out   = (float*)d_out;

    const bool big = ws_size >= (size_t)(131072 + 32 * 112 * 112 * 4);  // 1,736,704 B
    const int LDS_BYTES = 118784;

    if (big) {
        hipLaunchKernelGGL((prep_kernel<true>), dim3(512), dim3(256), 0, stream,
                           qkv_w, proj_w, rpb_tab, rel_idx, wqkv, wproj, btab);
        (void)hipFuncSetAttribute((const void*)(swin_main<true>),
                                  hipFuncAttributeMaxDynamicSharedMemorySize, LDS_BYTES);
        hipLaunchKernelGGL((swin_main<true>), dim3(2048), dim3(1024), LDS_BYTES, stream,
                           x, qkv_b, proj_b, wqkv, wproj, btab, out);
    } else {
        hipLaunchKernelGGL((prep_kernel<false>), dim3(512), dim3(256), 0, stream,
                           qkv_w, proj_w, rpb_tab, rel_idx, wqkv, wproj, btab);
        (void)hipFuncSetAttribute((const void*)(swin_main<false>),
                                  hipFuncAttributeMaxDynamicSharedMemorySize, LDS_BYTES);
        hipLaunchKernelGGL((swin_main<false>), dim3(2048), dim3(1024), LDS_BYTES, stream,
                           x, qkv_b, proj_b, wqkv, wproj, btab, out);
    }
}

// Round 12
// 124.937 us; speedup vs baseline: 1.3505x; 1.1305x over previous
//
#include <hip/hip_runtime.h>
#include <math.h>
#include <stdint.h>

// Video Swin shifted-window attention, fully fused, one block per window.
// Round 12: LDS shrunk to 78880 B/block -> TWO independent blocks per CU
// (32 waves/CU, separate barrier groups -- the latency-hiding R9/R10 failed
// to get). Layout:
//   q_w [98][128] swz (O overwrites in phase 2; disjoint (h,it) regions)
//   k_w [98][128] swz
//   xv_w: x[112][128] swz during phase 1, then vT[128][112] LINEAR (stride
//         112 ush = 14 chunks -> bijective bank rotation; v rides in regs
//         across the x->vT barrier). +16-ush zeroed pad absorbs the jt4=3
//         fragment wrap (garbage x 0 must be finite, not stale inf/NaN).
// q/k OOB fragment rows (98..111) land in the next finite region; outputs
// from those rows are discarded by the existing tok<98 guards.
// Phase 2 = R11's shfl-P no-max softmax (no p_lds needed).
// __launch_bounds__(1024,8): 2 blocks/CU needs VGPR<=64 (R11 used 48).

#define LOG2E   1.4426950408889634f
#define MASKNEG (-144.26950408889634f)   // -100 * LOG2E

typedef __attribute__((ext_vector_type(8)))  short    bf16x8;
typedef __attribute__((ext_vector_type(4)))  float    f32x4;
typedef __attribute__((ext_vector_type(4)))  unsigned uint32x4;

__device__ __forceinline__ unsigned short cvt1(float f) {
    __bf16 h = (__bf16)f;
    return __builtin_bit_cast(unsigned short, h);
}
__device__ __forceinline__ unsigned cvt2(float lo, float hi) {
    return (unsigned)cvt1(lo) | ((unsigned)cvt1(hi) << 16);
}

// token region code for the shifted-window mask (WIN=(2,7,7), SHIFT=(1,3,3))
__device__ __forceinline__ int tok_code(int t) {
    int pd = t / 49;
    int r  = t - pd * 49;
    int ph = r / 7;
    int pw = r - ph * 7;
    return (pd >= 1 ? 1 : 0) | (ph >= 4 ? 2 : 0) | (pw >= 4 ? 4 : 0);
}

__device__ __forceinline__ float mterm(unsigned pk, int sh, unsigned ci, unsigned cls) {
    return ((((pk >> sh) & 255u) ^ ci) & cls) ? MASKNEG : 0.f;
}

// XOR-swizzled element offset, [rows][128]-bf16 tiles (16B chunks)
__device__ __forceinline__ int swz(int row, int col) {
    return row * 128 + (((col >> 3) ^ (row & 7)) << 3) + (col & 7);
}

// ---------------- prep: weights -> bf16, bias tables ----------------
template<bool BIG>
__global__ void prep_kernel(const float* __restrict__ qkv_w,
                            const float* __restrict__ proj_w,
                            const float* __restrict__ rpb_table,
                            const int*   __restrict__ rel_index,
                            unsigned short* __restrict__ wqkv,
                            unsigned short* __restrict__ wproj,
                            void* __restrict__ btab) {
    int tid = blockIdx.x * blockDim.x + threadIdx.x;
    int stride = gridDim.x * blockDim.x;
    for (int i = tid; i < 384 * 128; i += stride) wqkv[i]  = cvt1(qkv_w[i]);
    for (int i = tid; i < 128 * 128; i += stride) wproj[i] = cvt1(proj_w[i]);
    if constexpr (BIG) {
        // bm[cls 8][h 4][i 112][j 112] f32: (bias + mask)*LOG2E; j>=98 -> -inf
        float* bm = (float*)btab;
        for (int idx = tid; idx < 32 * 112 * 112; idx += stride) {
            int ch = idx / 12544; int r = idx - ch * 12544;
            int i  = r / 112;     int j = r - i * 112;
            int cls = ch >> 2, h = ch & 3;
            float v;
            if (i < 98) {
                if (j < 98) {
                    float bias = rpb_table[rel_index[i * 98 + j] * 4 + h];
                    bool  msk  = (((unsigned)tok_code(i) ^ (unsigned)tok_code(j)) & (unsigned)cls) != 0;
                    v = bias * LOG2E + (msk ? MASKNEG : 0.f);
                } else v = -INFINITY;
            } else v = 0.f;
            bm[idx] = v;
        }
    } else {
        unsigned short* biasL = (unsigned short*)btab;
        for (int idx = tid; idx < 4 * 112 * 112; idx += stride) {
            int h = idx / 12544; int r = idx - h * 12544;
            int i = r / 112;     int j = r - i * 112;
            float v;
            if (i < 98) v = (j < 98) ? rpb_table[rel_index[i * 98 + j] * 4 + h] * LOG2E
                                     : -INFINITY;
            else v = 0.f;
            biasL[idx] = cvt1(v);
        }
    }
}

// ---------------- main fused kernel ----------------
template<bool BIG>
__global__ __launch_bounds__(1024, 8)
void swin_main(const float* __restrict__ x,
               const float* __restrict__ qkv_b,
               const float* __restrict__ proj_b,
               const unsigned short* __restrict__ wqkv,
               const unsigned short* __restrict__ wproj,
               const void* __restrict__ btab,
               float* __restrict__ out)
{
    extern __shared__ unsigned short lds[];
    unsigned short* q_w  = lds;            // q[98][128] swz; O overwrites
    unsigned short* k_w  = lds + 12544;    // k[98][128] swz
    unsigned short* xv_w = lds + 25088;    // x[112][128] swz -> vT[128][112] linear; +16 pad
    // total 39440 ush = 78880 B -> 2 blocks/CU

    const int b    = blockIdx.x;
    const int tid  = threadIdx.x;
    const int wv   = tid >> 6;    // 0..15
    const int lane = tid & 63;
    const int l4   = lane >> 4;   // 0..3
    const int lc   = lane & 15;   // 0..15

    // zero the 16-ush fragment-wrap pad (stale inf/NaN x 0 = NaN poison)
    if (tid < 8) *(unsigned*)(xv_w + 14336 + tid * 2) = 0u;

    // stage x -> xv_w swz (pad rows 98..111 zeroed)
    {
        const float* xb = x + (size_t)b * 12544;
#pragma unroll
        for (int i = 0; i < 4; ++i) {
            int idx = tid + i * 1024;
            if (idx >= 3584) break;
            int tok = idx >> 5;
            int c   = (idx & 31) << 2;
            float4 v;
            if (tok < 98) v = *(const float4*)(xb + tok * 128 + c);
            else { v.x = 0.f; v.y = 0.f; v.z = 0.f; v.w = 0.f; }
            uint2 hv; hv.x = cvt2(v.x, v.y); hv.y = cvt2(v.z, v.w);
            *(uint2*)(xv_w + swz(tok, c)) = hv;
        }
    }
    __syncthreads();

    // ---- Phase 1A: q,k tiles (wave ct: q<8 scaled, k>=8) ----
    {
        const int ct = wv;
        bf16x8 wf[4];
        f32x4  bias;
        const unsigned short* wrow = wqkv + (ct * 16 + lc) * 128;
#pragma unroll
        for (int kt = 0; kt < 4; ++kt) wf[kt] = *(const bf16x8*)(wrow + kt * 32 + l4 * 8);
#pragma unroll
        for (int r = 0; r < 4; ++r) bias[r] = qkv_b[ct * 16 + l4 * 4 + r];
        const bool  isq = (ct < 8);
        const float qs  = 0.17677669529663689f * LOG2E;
#pragma unroll
        for (int t = 0; t < 7; ++t) {
            bf16x8 xf[4];
#pragma unroll
            for (int kt = 0; kt < 4; ++kt)
                xf[kt] = *(bf16x8*)(xv_w + swz(t * 16 + lc, kt * 32 + l4 * 8));
            f32x4 acc = bias;
#pragma unroll
            for (int kt = 0; kt < 4; ++kt)
                acc = __builtin_amdgcn_mfma_f32_16x16x32_bf16(wf[kt], xf[kt], acc, 0, 0, 0);
            int tok = t * 16 + lc;
            if (tok < 98) {
                if (isq) {
                    uint2 hv; hv.x = cvt2(acc[0] * qs, acc[1] * qs); hv.y = cvt2(acc[2] * qs, acc[3] * qs);
                    *(uint2*)(q_w + swz(tok, ct * 16 + l4 * 4)) = hv;
                } else {
                    uint2 hv; hv.x = cvt2(acc[0], acc[1]); hv.y = cvt2(acc[2], acc[3]);
                    *(uint2*)(k_w + swz(tok, (ct - 8) * 16 + l4 * 4)) = hv;
                }
            }
        }
    }

    // ---- Phase 1B: v tiles into registers (x still live) ----
    f32x4 vacc[4];
    const int vd = (wv >> 1) * 16;
    const int t0 = (wv & 1) ? 4 : 0;
    const int nt = (wv & 1) ? 3 : 4;
    {
        bf16x8 wf2[4];
        const unsigned short* wrow2 = wqkv + (256 + vd + lc) * 128;
#pragma unroll
        for (int kt = 0; kt < 4; ++kt) wf2[kt] = *(const bf16x8*)(wrow2 + kt * 32 + l4 * 8);
        f32x4 bias2;
#pragma unroll
        for (int r = 0; r < 4; ++r) bias2[r] = qkv_b[256 + vd + l4 * 4 + r];
#pragma unroll
        for (int ti = 0; ti < 4; ++ti) {
            if (ti >= nt) break;
            int t = t0 + ti;
            bf16x8 xf[4];
#pragma unroll
            for (int kt = 0; kt < 4; ++kt)
                xf[kt] = *(bf16x8*)(xv_w + swz(t * 16 + lc, kt * 32 + l4 * 8));
            f32x4 acc = bias2;
#pragma unroll
            for (int kt = 0; kt < 4; ++kt)
                acc = __builtin_amdgcn_mfma_f32_16x16x32_bf16(wf2[kt], xf[kt], acc, 0, 0, 0);
            vacc[ti] = acc;
        }
    }
    __syncthreads();   // all x reads complete

    // ---- Phase 1C: vT[128][112] linear over the x region ----
    {
#pragma unroll
        for (int ti = 0; ti < 4; ++ti) {
            if (ti >= nt) break;
            int tok = (t0 + ti) * 16 + lc;
            const int rb = vd + l4 * 4;
            xv_w[(rb + 0) * 112 + tok] = cvt1(vacc[ti][0]);
            xv_w[(rb + 1) * 112 + tok] = cvt1(vacc[ti][1]);
            xv_w[(rb + 2) * 112 + tok] = cvt1(vacc[ti][2]);
            xv_w[(rb + 3) * 112 + tok] = cvt1(vacc[ti][3]);
        }
    }
    __syncthreads();

    // ---- Phase 2: attention. 28 tasks over 16 waves, 2 passes (R11 shfl-P) ----
    const int wi  = b & 255;
    const unsigned int cls =
        ((wi >> 6) == 3 ? 1u : 0u) | (((wi >> 3) & 7) == 7 ? 2u : 0u) | ((wi & 7) == 7 ? 4u : 0u);

    unsigned int jcp[7];   // packed region codes (small path only)
    if constexpr (!BIG) {
#pragma unroll
        for (int jt = 0; jt < 7; ++jt) {
            int jb = jt * 16 + l4 * 4;
            unsigned int p = 0;
#pragma unroll
            for (int r = 0; r < 4; ++r) p |= (unsigned)tok_code(jb + r < 98 ? jb + r : 0) << (8 * r);
            jcp[jt] = p;
        }
    }

    const int  srcA = ((l4 & 1) * 2) * 16 + lc;   // P-redistribution source lanes
    const int  srcB = srcA + 16;
    const bool phi  = (l4 >> 1) != 0;

    for (int pass = 0; pass < 2; ++pass) {
        int task = wv + (pass << 4);
        if (task >= 28) break;
        int h  = task / 7;
        int it = task - h * 7;
        const int i_tok = it * 16 + lc;
        const bf16x8 qfrag = *(bf16x8*)(q_w + swz(i_tok, h * 32 + l4 * 8));

        f32x4 cvec[7];
        if constexpr (BIG) {
            const float* bmrow = (const float*)btab + ((size_t)((int)cls * 4 + h) * 112 + i_tok) * 112;
#pragma unroll
            for (int jt = 0; jt < 7; ++jt)
                cvec[jt] = *(const f32x4*)(bmrow + jt * 16 + l4 * 4);
        } else {
            const unsigned short* brow = (const unsigned short*)btab + (h * 112 + i_tok) * 112;
            const unsigned int ci = (unsigned)tok_code(i_tok < 98 ? i_tok : 0);
            ushort4 bb[7];
#pragma unroll
            for (int jt = 0; jt < 7; ++jt)
                bb[jt] = *(const ushort4*)(brow + jt * 16 + l4 * 4);
#pragma unroll
            for (int jt = 0; jt < 7; ++jt) {
                cvec[jt][0] = __builtin_bit_cast(float, (unsigned)bb[jt].x << 16) + mterm(jcp[jt], 0,  ci, cls);
                cvec[jt][1] = __builtin_bit_cast(float, (unsigned)bb[jt].y << 16) + mterm(jcp[jt], 8,  ci, cls);
                cvec[jt][2] = __builtin_bit_cast(float, (unsigned)bb[jt].z << 16) + mterm(jcp[jt], 16, ci, cls);
                cvec[jt][3] = __builtin_bit_cast(float, (unsigned)bb[jt].w << 16) + mterm(jcp[jt], 24, ci, cls);
            }
        }

        f32x4 s[7];
#pragma unroll
        for (int jt = 0; jt < 7; ++jt) {
            bf16x8 kfrag = *(bf16x8*)(k_w + swz(jt * 16 + lc, h * 32 + l4 * 8));
            s[jt] = __builtin_amdgcn_mfma_f32_16x16x32_bf16(kfrag, qfrag, cvec[jt], 0, 0, 0);
        }

        // no-max softmax: exp2 directly (masked/pad -> -inf -> 0); pack to bf16
        float lsum = 0.f;
        unsigned dw[8][2];
#pragma unroll
        for (int jt = 0; jt < 7; ++jt) {
            float p0 = exp2f(s[jt][0]);
            float p1 = exp2f(s[jt][1]);
            float p2 = exp2f(s[jt][2]);
            float p3 = exp2f(s[jt][3]);
            lsum += (p0 + p1) + (p2 + p3);
            dw[jt][0] = cvt2(p0, p1);
            dw[jt][1] = cvt2(p2, p3);
        }
        dw[7][0] = 0u; dw[7][1] = 0u;   // j = 112..127: zero B kills wrapped A garbage

        // PV with in-register P redistribution; vT linear stride 112
        f32x4 o0 = {0.f, 0.f, 0.f, 0.f}, o1 = {0.f, 0.f, 0.f, 0.f};
#pragma unroll
        for (int jt4 = 0; jt4 < 4; ++jt4) {
            unsigned a0 = dw[2 * jt4][0],     a1 = dw[2 * jt4][1];
            unsigned b0 = dw[2 * jt4 + 1][0], b1 = dw[2 * jt4 + 1][1];
            unsigned xA0 = __shfl((int)a0, srcA), yA0 = __shfl((int)b0, srcA);
            unsigned xA1 = __shfl((int)a1, srcA), yA1 = __shfl((int)b1, srcA);
            unsigned xB0 = __shfl((int)a0, srcB), yB0 = __shfl((int)b0, srcB);
            unsigned xB1 = __shfl((int)a1, srcB), yB1 = __shfl((int)b1, srcB);
            uint32x4 pu = { phi ? yA0 : xA0, phi ? yA1 : xA1,
                            phi ? yB0 : xB0, phi ? yB1 : xB1 };
            bf16x8 pfrag = __builtin_bit_cast(bf16x8, pu);
            bf16x8 va = *(bf16x8*)(xv_w + (h * 32 + lc) * 112      + jt4 * 32 + l4 * 8);
            bf16x8 vb = *(bf16x8*)(xv_w + (h * 32 + 16 + lc) * 112 + jt4 * 32 + l4 * 8);
            o0 = __builtin_amdgcn_mfma_f32_16x16x32_bf16(va, pfrag, o0, 0, 0, 0);
            o1 = __builtin_amdgcn_mfma_f32_16x16x32_bf16(vb, pfrag, o1, 0, 0, 0);
        }
        lsum += __shfl_xor(lsum, 16);
        lsum += __shfl_xor(lsum, 32);

        float inv = 1.0f / lsum;
        if (i_tok < 98) {
            uint2 h0, h1;
            h0.x = cvt2(o0[0] * inv, o0[1] * inv); h0.y = cvt2(o0[2] * inv, o0[3] * inv);
            h1.x = cvt2(o1[0] * inv, o1[1] * inv); h1.y = cvt2(o1[2] * inv, o1[3] * inv);
            *(uint2*)(q_w + swz(i_tok, h * 32 + l4 * 4)) = h0;        // O over q
            *(uint2*)(q_w + swz(i_tok, h * 32 + 16 + l4 * 4)) = h1;
        }
    }
    __syncthreads();

    // ---- Phase 3: y^T = Wproj @ O^T (O in q region) ----
    {
        const int ct = wv >> 1;
        bf16x8 pw[4];
#pragma unroll
        for (int kt = 0; kt < 4; ++kt)
            pw[kt] = *(const bf16x8*)(wproj + (ct * 16 + lc) * 128 + kt * 32 + l4 * 8);
        f32x4 pbias;
#pragma unroll
        for (int r = 0; r < 4; ++r) pbias[r] = proj_b[ct * 16 + l4 * 4 + r];

        float* ob = out + (size_t)b * 12544;
        const int tt0 = (wv & 1) ? 4 : 0, tt1 = (wv & 1) ? 7 : 4;
        for (int t = tt0; t < tt1; ++t) {
            f32x4 acc = pbias;
#pragma unroll
            for (int kt = 0; kt < 4; ++kt) {
                bf16x8 of = *(bf16x8*)(q_w + swz(t * 16 + lc, kt * 32 + l4 * 8));
                acc = __builtin_amdgcn_mfma_f32_16x16x32_bf16(pw[kt], of, acc, 0, 0, 0);
            }
            int tok = t * 16 + lc;
            if (tok < 98) {
                float4 st; st.x = acc[0]; st.y = acc[1]; st.z = acc[2]; st.w = acc[3];
                *(float4*)(ob + tok * 128 + ct * 16 + l4 * 4) = st;
            }
        }
    }
}

extern "C" void kernel_launch(void* const* d_in, const int* in_sizes, int n_in,
                              void* d_out, int out_size, void* d_ws, size_t ws_size,
                              hipStream_t stream) {
    const float* x       = (const float*)d_in[0];
    const float* qkv_w   = (const float*)d_in[1];
    const float* qkv_b   = (const float*)d_in[2];
    const float* rpb_tab = (const float*)d_in[3];
    const float* proj_w  = (const float*)d_in[4];
    const float* proj_b  = (const float*)d_in[5];
    const int*   rel_idx = (const int*)d_in[6];
    // d_in[7] (mask) unused: reproduced analytically into the tables.

    unsigned short* wqkv  = (unsigned short*)d_ws;                   // 98304 B
    unsigned short* wproj = (unsigned short*)((char*)d_ws + 98304);  // 32768 B
    void*           btab  = (void*)((char*)d_ws + 131072);           // bias table
    float*          out   = (float*)d_out;

    const bool big = ws_size >= (size_t)(131072 + 32 * 112 * 112 * 4);  // 1,736,704 B
    const int LDS_BYTES = 78880;

    if (big) {
        hipLaunchKernelGGL((prep_kernel<true>), dim3(512), dim3(256), 0, stream,
                           qkv_w, proj_w, rpb_tab, rel_idx, wqkv, wproj, btab);
        (void)hipFuncSetAttribute((const void*)(swin_main<true>),
                                  hipFuncAttributeMaxDynamicSharedMemorySize, LDS_BYTES);
        hipLaunchKernelGGL((swin_main<true>), dim3(2048), dim3(1024), LDS_BYTES, stream,
                           x, qkv_b, proj_b, wqkv, wproj, btab, out);
    } else {
        hipLaunchKernelGGL((prep_kernel<false>), dim3(512), dim3(256), 0, stream,
                           qkv_w, proj_w, rpb_tab, rel_idx, wqkv, wproj, btab);
        (void)hipFuncSetAttribute((const void*)(swin_main<false>),
                                  hipFuncAttributeMaxDynamicSharedMemorySize, LDS_BYTES);
        hipLaunchKernelGGL((swin_main<false>), dim3(2048), dim3(1024), LDS_BYTES, stream,
                           x, qkv_b, proj_b, wqkv, wproj, btab, out);
    }
}